// Round 2
// baseline (636.868 us; speedup 1.0000x reference)
//
#include <hip/hip_runtime.h>
#include <float.h>

// z: (64,32,32,64) fp32 -> N=65536 rows, D=64 ; codebook: (1024,64) fp32
// out concat fp32: zq [N*64] | tokens-as-float [N] | codebook [1024*64]
constexpr int D     = 64;
constexpr int V     = 1024;
constexpr int NROWS = 65536;
constexpr float MARGIN = 0.25f;   // >= 2x worst-case f16 screen error vs np fp32

typedef _Float16 half8 __attribute__((ext_vector_type(8)));
typedef float    f32x4 __attribute__((ext_vector_type(4)));

// ---------------- main MFMA screen kernel ----------------
// 256 blocks x 512 threads (8 waves). Wave gw handles rows [gw*32, gw*32+32)
// as two 16-row MFMA tiles sharing B-fragments. Codebook staged to LDS as f16
// in 4 phases of 256 codewords, chunk-major: sB[k_octet][cw][8 f16] so a
// B-frag (B[k=quad*8+j][n=lane&15]) is one aligned ds_read_b128.
__global__ __launch_bounds__(512, 2) void vq_mfma(
    const float* __restrict__ z, const float* __restrict__ cb,
    float* __restrict__ zq, float* __restrict__ tok, float* __restrict__ cbout,
    int* __restrict__ cnt, int* __restrict__ list) {
  __shared__ __align__(16) _Float16 sB[8][256][8];  // 32 KiB
  __shared__ float sC2[512];                        // |c|^2 partials: [cw*2+half]
  __shared__ int   sW[8][32];                       // winner idx per wave-row

  const int tid  = threadIdx.x;
  const int lane = tid & 63;
  const int wv   = tid >> 6;        // wave in block, 0..7
  const int l15  = lane & 15;
  const int quad = lane >> 4;       // 0..3
  const int gw   = blockIdx.x * 8 + wv;
  const int rowbase = gw * 32;

  // codebook passthrough (no separate memcpy dispatch): 64 float4 per block
  if (tid < 64)
    ((float4*)cbout)[blockIdx.x * 64 + tid] = ((const float4*)cb)[blockIdx.x * 64 + tid];

  // ---- A fragments: rows rowbase + rt*16 + l15, k = quad*8 + j (+32*h) ----
  half8 afr[2][2];
#pragma unroll
  for (int rt = 0; rt < 2; ++rt) {
    const float* zr = z + (size_t)(rowbase + rt * 16 + l15) * D;
#pragma unroll
    for (int h = 0; h < 2; ++h) {
      const float4* p = (const float4*)(zr + h * 32 + quad * 8);
      float4 q0 = p[0], q1 = p[1];
      half8 a;
      a[0] = (_Float16)q0.x; a[1] = (_Float16)q0.y; a[2] = (_Float16)q0.z; a[3] = (_Float16)q0.w;
      a[4] = (_Float16)q1.x; a[5] = (_Float16)q1.y; a[6] = (_Float16)q1.z; a[7] = (_Float16)q1.w;
      afr[rt][h] = a;
    }
  }

  // per-lane state: best/second-best screen value + best index, 4 C-regs x 2 row-tiles
  float b1[2][4], b2[2][4]; int i1[2][4];
#pragma unroll
  for (int rt = 0; rt < 2; ++rt)
#pragma unroll
    for (int r = 0; r < 4; ++r) { b1[rt][r] = FLT_MAX; b2[rt][r] = FLT_MAX; i1[rt][r] = 0; }

  for (int phase = 0; phase < 4; ++phase) {
    __syncthreads();  // previous compute done before LDS overwrite
    // ---- stage 256 codewords fp32->fp16 + |c|^2 half-partials ----
    {
      const int cwl   = tid & 255;   // this thread's codeword (constant over i)
      const int chalf = tid >> 8;    // 0: even k-octets, 1: odd
      float part = 0.f;
#pragma unroll
      for (int i = 0; i < 4; ++i) {
        const int chunk = chalf + 2 * i;
        const float* src = cb + (size_t)(phase * 256 + cwl) * D + chunk * 8;
        float4 q0 = ((const float4*)src)[0], q1 = ((const float4*)src)[1];
        half8 hh;
        hh[0] = (_Float16)q0.x; hh[1] = (_Float16)q0.y; hh[2] = (_Float16)q0.z; hh[3] = (_Float16)q0.w;
        hh[4] = (_Float16)q1.x; hh[5] = (_Float16)q1.y; hh[6] = (_Float16)q1.z; hh[7] = (_Float16)q1.w;
        *(half8*)&sB[chunk][cwl][0] = hh;
        part = fmaf(q0.x, q0.x, part); part = fmaf(q0.y, q0.y, part);
        part = fmaf(q0.z, q0.z, part); part = fmaf(q0.w, q0.w, part);
        part = fmaf(q1.x, q1.x, part); part = fmaf(q1.y, q1.y, part);
        part = fmaf(q1.z, q1.z, part); part = fmaf(q1.w, q1.w, part);
      }
      sC2[cwl * 2 + chalf] = part;
    }
    __syncthreads();
    // ---- 16 col-tiles of 16 codewords each ----
    for (int tl = 0; tl < 16; ++tl) {
      const int cwl  = tl * 16 + l15;
      const int vcol = phase * 256 + cwl;
      float2 c2p = *(const float2*)&sC2[cwl * 2];
      const float c2v = c2p.x + c2p.y;
      half8 bf0 = *(const half8*)&sB[quad][cwl][0];      // k = quad*8+j
      half8 bf1 = *(const half8*)&sB[4 + quad][cwl][0];  // k = 32+quad*8+j
      f32x4 acc0 = {0.f, 0.f, 0.f, 0.f}, acc1 = {0.f, 0.f, 0.f, 0.f};
      acc0 = __builtin_amdgcn_mfma_f32_16x16x32_f16(afr[0][0], bf0, acc0, 0, 0, 0);
      acc0 = __builtin_amdgcn_mfma_f32_16x16x32_f16(afr[0][1], bf1, acc0, 0, 0, 0);
      acc1 = __builtin_amdgcn_mfma_f32_16x16x32_f16(afr[1][0], bf0, acc1, 0, 0, 0);
      acc1 = __builtin_amdgcn_mfma_f32_16x16x32_f16(afr[1][1], bf1, acc1, 0, 0, 0);
#pragma unroll
      for (int r = 0; r < 4; ++r) {
        float m0 = fmaf(-2.f, acc0[r], c2v);
        bool  c0 = m0 < b1[0][r];
        b2[0][r] = fminf(b2[0][r], fmaxf(m0, b1[0][r]));
        b1[0][r] = c0 ? m0 : b1[0][r];
        i1[0][r] = c0 ? vcol : i1[0][r];
        float m1 = fmaf(-2.f, acc1[r], c2v);
        bool  c1 = m1 < b1[1][r];
        b2[1][r] = fminf(b2[1][r], fmaxf(m1, b1[1][r]));
        b1[1][r] = c1 ? m1 : b1[1][r];
        i1[1][r] = c1 ? vcol : i1[1][r];
      }
    }
  }

  // ---- cross-lane reduce over the 16 col-lanes of each quad group ----
  // C layout: row = quad*4 + reg (within tile), col = l15. XOR 1/2/4/8 stays in-group.
#pragma unroll
  for (int rt = 0; rt < 2; ++rt)
#pragma unroll
    for (int r = 0; r < 4; ++r) {
      float v1 = b1[rt][r], v2 = b2[rt][r]; int ix = i1[rt][r];
#pragma unroll
      for (int s = 1; s < 16; s <<= 1) {
        float ov1 = __shfl_xor(v1, s);
        float ov2 = __shfl_xor(v2, s);
        int   oix = __shfl_xor(ix, s);
        bool take = (ov1 < v1) || (ov1 == v1 && oix < ix);  // np first-occurrence ties
        float worse = take ? v1 : ov1;
        v2 = fminf(fminf(v2, ov2), worse);
        v1 = take ? ov1 : v1;
        ix = take ? oix : ix;
      }
      b1[rt][r] = v1; b2[rt][r] = v2; i1[rt][r] = ix;
    }

  // writers: one lane per quad group publishes winners + flags ambiguous rows
  if (l15 == 0) {
#pragma unroll
    for (int rt = 0; rt < 2; ++rt)
#pragma unroll
      for (int r = 0; r < 4; ++r) {
        int rl = rt * 16 + quad * 4 + r;
        sW[wv][rl] = i1[rt][r];
        if (b2[rt][r] - b1[rt][r] < MARGIN) {   // screen can't certify argmin
          int slot = atomicAdd(cnt, 1);
          list[slot] = rowbase + rl;
        }
      }
  }
  __syncthreads();

  // tokens (as float; whole out buffer is fp32)
  if (lane < 32) tok[rowbase + lane] = (float)sW[wv][lane];

  // zq gather from fp32 codebook: 32 rows x 16 chunks of 16B, 8 per lane
#pragma unroll
  for (int i = 0; i < 8; ++i) {
    int cid = i * 64 + lane;
    int r32 = cid >> 4, seg = cid & 15;
    int widx = sW[wv][r32];
    float4 val = *(const float4*)(cb + (size_t)widx * D + seg * 4);
    *(float4*)(zq + (size_t)(rowbase + r32) * D + seg * 4) = val;
  }
}

// ---------------- exact fallback for flagged rows ----------------
// Reproduces round-1's arithmetic exactly (sequential fmaf; that kernel
// matched np with absmax=0 on all rows). One block per flagged row.
__global__ __launch_bounds__(256) void vq_fallback(
    const float* __restrict__ z, const float* __restrict__ cb,
    const int* __restrict__ cnt, const int* __restrict__ list,
    float* __restrict__ zq, float* __restrict__ tok) {
  __shared__ float sv[256];
  __shared__ int   si[256];
  const int t = threadIdx.x;
  const int n = cnt[0];
  for (int it = blockIdx.x; it < n; it += gridDim.x) {
    int row = __builtin_amdgcn_readfirstlane(list[it]);
    const float* zr = z + (size_t)row * D;
    float zreg[D];
#pragma unroll
    for (int i = 0; i < D / 4; ++i) {
      float4 q = ((const float4*)zr)[i];
      zreg[4 * i] = q.x; zreg[4 * i + 1] = q.y; zreg[4 * i + 2] = q.z; zreg[4 * i + 3] = q.w;
    }
    float d1 = 0.f;
#pragma unroll
    for (int i = 0; i < D; ++i) d1 = fmaf(zreg[i], zreg[i], d1);
    float best = FLT_MAX; int bidx = 0;
    for (int c = 0; c < 4; ++c) {
      int v = t + 256 * c;
      const float* cp = cb + (size_t)v * D;
      float acc = 0.f, cc = 0.f;
#pragma unroll
      for (int dd = 0; dd < D; ++dd) {
        acc = fmaf(zreg[dd], cp[dd], acc);
        cc  = fmaf(cp[dd], cp[dd], cc);
      }
      float dist = (d1 + cc) - 2.f * acc;
      if (dist < best) { best = dist; bidx = v; }
    }
    sv[t] = best; si[t] = bidx;
    __syncthreads();
    for (int s = 128; s > 0; s >>= 1) {
      if (t < s) {
        float v2 = sv[t + s]; int i2 = si[t + s];
        if (v2 < sv[t] || (v2 == sv[t] && i2 < si[t])) { sv[t] = v2; si[t] = i2; }
      }
      __syncthreads();
    }
    int win = si[0];
    if (t == 0) tok[row] = (float)win;
    if (t < 16) {
      float4 q = ((const float4*)(cb + (size_t)win * D))[t];
      ((float4*)(zq + (size_t)row * D))[t] = q;
    }
    __syncthreads();  // sv/si reused next iteration
  }
}

extern "C" void kernel_launch(void* const* d_in, const int* in_sizes, int n_in,
                              void* d_out, int out_size, void* d_ws, size_t ws_size,
                              hipStream_t stream) {
  const float* z  = (const float*)d_in[0];
  const float* cb = (const float*)d_in[1];

  float* out = (float*)d_out;
  float* zq  = out;                      // [NROWS*D]
  float* tok = out + (size_t)NROWS * D;  // [NROWS]
  float* cbo = tok + NROWS;              // [V*D]

  int* cnt  = (int*)d_ws;                // [1], zeroed below
  int* list = (int*)d_ws + 64;           // [NROWS] flagged rows (cap = worst case)

  hipMemsetAsync(cnt, 0, sizeof(int), stream);
  vq_mfma<<<256, 512, 0, stream>>>(z, cb, zq, tok, cbo, cnt, list);
  vq_fallback<<<1024, 256, 0, stream>>>(z, cb, cnt, list, zq, tok);
}

// Round 3
// 208.401 us; speedup vs baseline: 3.0560x; 3.0560x over previous
//
#include <hip/hip_runtime.h>
#include <float.h>

// z: (64,32,32,64) fp32 -> N=65536 rows, D=64 ; codebook: (1024,64) fp32
// out concat fp32: zq [N*64] | tokens-as-float [N] | codebook [1024*64]
constexpr int D     = 64;
constexpr int V     = 1024;
constexpr int NROWS = 65536;
// Screen: split-f16 dot (zh*ch + zh*cl + zl*ch), |err| <= ~1e-4 vs exact;
// np's own fp32 rounding <= ~1e-4. MARGIN 0.01 gives >=30x safety.
constexpr float MARGIN = 0.01f;

typedef _Float16 half8 __attribute__((ext_vector_type(8)));
typedef float    f32x4 __attribute__((ext_vector_type(4)));

// ---------------- main MFMA screen kernel ----------------
// 256 blocks x 512 threads (8 waves). Wave gw -> rows [gw*32, gw*32+32) as two
// 16-row MFMA tiles sharing B-fragments. Codebook staged to LDS as f16 hi+lo
// in 4 phases of 256 codewords, chunk-major: sB*[k_octet][cw][8] so a B-frag
// (B[k=quad*8+j][n=lane&15]) is one aligned ds_read_b128.
__global__ __launch_bounds__(512, 2) void vq_mfma(
    const float* __restrict__ z, const float* __restrict__ cb,
    float* __restrict__ zq, float* __restrict__ tok, float* __restrict__ cbout,
    int* __restrict__ cnt, int* __restrict__ list) {
  __shared__ __align__(16) _Float16 sBh[8][256][8];  // 32 KiB (hi)
  __shared__ __align__(16) _Float16 sBl[8][256][8];  // 32 KiB (lo)
  __shared__ float sC2[512];                         // |c|^2 partials [cw*2+half]
  __shared__ int   sW[8][32];                        // winner idx per wave-row
  __shared__ int   sFlagRows[256];
  __shared__ int   sFlagCnt, sFlagBase;

  const int tid  = threadIdx.x;
  const int lane = tid & 63;
  const int wv   = tid >> 6;        // wave in block, 0..7
  const int l15  = lane & 15;
  const int quad = lane >> 4;       // 0..3
  const int gw   = blockIdx.x * 8 + wv;
  const int rowbase = gw * 32;

  if (tid == 0) sFlagCnt = 0;

  // codebook passthrough: 64 float4 per block
  if (tid < 64)
    ((float4*)cbout)[blockIdx.x * 64 + tid] = ((const float4*)cb)[blockIdx.x * 64 + tid];

  // ---- A fragments hi/lo: rows rowbase + rt*16 + l15, k = quad*8 + j (+32*h) ----
  half8 afh[2][2], afl[2][2];
#pragma unroll
  for (int rt = 0; rt < 2; ++rt) {
    const float* zr = z + (size_t)(rowbase + rt * 16 + l15) * D;
#pragma unroll
    for (int h = 0; h < 2; ++h) {
      const float4* p = (const float4*)(zr + h * 32 + quad * 8);
      float4 q0 = p[0], q1 = p[1];
      float xs[8] = {q0.x, q0.y, q0.z, q0.w, q1.x, q1.y, q1.z, q1.w};
      half8 ah, al;
#pragma unroll
      for (int e = 0; e < 8; ++e) {
        _Float16 hi = (_Float16)xs[e];
        ah[e] = hi;
        al[e] = (_Float16)(xs[e] - (float)hi);
      }
      afh[rt][h] = ah; afl[rt][h] = al;
    }
  }

  // per-lane best / second-best screen value + best index, 4 C-regs x 2 row-tiles
  float b1[2][4], b2[2][4]; int i1[2][4];
#pragma unroll
  for (int rt = 0; rt < 2; ++rt)
#pragma unroll
    for (int r = 0; r < 4; ++r) { b1[rt][r] = FLT_MAX; b2[rt][r] = FLT_MAX; i1[rt][r] = 0; }

  for (int phase = 0; phase < 4; ++phase) {
    __syncthreads();  // previous compute done before LDS overwrite
    // ---- stage 256 codewords fp32 -> f16 hi+lo, plus |c|^2 half-partials ----
    {
      const int cwl   = tid & 255;
      const int chalf = tid >> 8;    // 0: even k-octets, 1: odd
      float part = 0.f;
#pragma unroll
      for (int i = 0; i < 4; ++i) {
        const int chunk = chalf + 2 * i;
        const float* src = cb + (size_t)(phase * 256 + cwl) * D + chunk * 8;
        float4 q0 = ((const float4*)src)[0], q1 = ((const float4*)src)[1];
        float xs[8] = {q0.x, q0.y, q0.z, q0.w, q1.x, q1.y, q1.z, q1.w};
        half8 hh, hl;
#pragma unroll
        for (int e = 0; e < 8; ++e) {
          _Float16 hi = (_Float16)xs[e];
          hh[e] = hi;
          hl[e] = (_Float16)(xs[e] - (float)hi);
          part  = fmaf(xs[e], xs[e], part);
        }
        *(half8*)&sBh[chunk][cwl][0] = hh;
        *(half8*)&sBl[chunk][cwl][0] = hl;
      }
      sC2[cwl * 2 + chalf] = part;
    }
    __syncthreads();
    // ---- 16 col-tiles of 16 codewords each ----
    for (int tl = 0; tl < 16; ++tl) {
      const int cwl  = tl * 16 + l15;
      const int vcol = phase * 256 + cwl;
      float2 c2p = *(const float2*)&sC2[cwl * 2];
      const float c2v = c2p.x + c2p.y;
      half8 bh0 = *(const half8*)&sBh[quad][cwl][0];      // k = quad*8+j
      half8 bh1 = *(const half8*)&sBh[4 + quad][cwl][0];  // k = 32+quad*8+j
      half8 bl0 = *(const half8*)&sBl[quad][cwl][0];
      half8 bl1 = *(const half8*)&sBl[4 + quad][cwl][0];
      f32x4 acc0 = {0.f, 0.f, 0.f, 0.f}, acc1 = {0.f, 0.f, 0.f, 0.f};
      // zh*ch
      acc0 = __builtin_amdgcn_mfma_f32_16x16x32_f16(afh[0][0], bh0, acc0, 0, 0, 0);
      acc0 = __builtin_amdgcn_mfma_f32_16x16x32_f16(afh[0][1], bh1, acc0, 0, 0, 0);
      // zh*cl
      acc0 = __builtin_amdgcn_mfma_f32_16x16x32_f16(afh[0][0], bl0, acc0, 0, 0, 0);
      acc0 = __builtin_amdgcn_mfma_f32_16x16x32_f16(afh[0][1], bl1, acc0, 0, 0, 0);
      // zl*ch
      acc0 = __builtin_amdgcn_mfma_f32_16x16x32_f16(afl[0][0], bh0, acc0, 0, 0, 0);
      acc0 = __builtin_amdgcn_mfma_f32_16x16x32_f16(afl[0][1], bh1, acc0, 0, 0, 0);

      acc1 = __builtin_amdgcn_mfma_f32_16x16x32_f16(afh[1][0], bh0, acc1, 0, 0, 0);
      acc1 = __builtin_amdgcn_mfma_f32_16x16x32_f16(afh[1][1], bh1, acc1, 0, 0, 0);
      acc1 = __builtin_amdgcn_mfma_f32_16x16x32_f16(afh[1][0], bl0, acc1, 0, 0, 0);
      acc1 = __builtin_amdgcn_mfma_f32_16x16x32_f16(afh[1][1], bl1, acc1, 0, 0, 0);
      acc1 = __builtin_amdgcn_mfma_f32_16x16x32_f16(afl[1][0], bh0, acc1, 0, 0, 0);
      acc1 = __builtin_amdgcn_mfma_f32_16x16x32_f16(afl[1][1], bh1, acc1, 0, 0, 0);
#pragma unroll
      for (int r = 0; r < 4; ++r) {
        float m0 = fmaf(-2.f, acc0[r], c2v);
        bool  c0 = m0 < b1[0][r];
        b2[0][r] = fminf(b2[0][r], fmaxf(m0, b1[0][r]));
        b1[0][r] = c0 ? m0 : b1[0][r];
        i1[0][r] = c0 ? vcol : i1[0][r];
        float m1 = fmaf(-2.f, acc1[r], c2v);
        bool  c1 = m1 < b1[1][r];
        b2[1][r] = fminf(b2[1][r], fmaxf(m1, b1[1][r]));
        b1[1][r] = c1 ? m1 : b1[1][r];
        i1[1][r] = c1 ? vcol : i1[1][r];
      }
    }
  }

  // ---- cross-lane reduce over the 16 col-lanes of each quad group ----
  // C layout: row = quad*4 + reg (within tile), col = l15. XOR 1/2/4/8 stays in-group.
#pragma unroll
  for (int rt = 0; rt < 2; ++rt)
#pragma unroll
    for (int r = 0; r < 4; ++r) {
      float v1 = b1[rt][r], v2 = b2[rt][r]; int ix = i1[rt][r];
#pragma unroll
      for (int s = 1; s < 16; s <<= 1) {
        float ov1 = __shfl_xor(v1, s);
        float ov2 = __shfl_xor(v2, s);
        int   oix = __shfl_xor(ix, s);
        bool take = (ov1 < v1) || (ov1 == v1 && oix < ix);  // np first-occurrence ties
        float worse = take ? v1 : ov1;
        v2 = fminf(fminf(v2, ov2), worse);
        v1 = take ? ov1 : v1;
        ix = take ? oix : ix;
      }
      b1[rt][r] = v1; b2[rt][r] = v2; i1[rt][r] = ix;
    }

  // writers: one lane per quad group publishes winners; flags queue in LDS
  if (l15 == 0) {
#pragma unroll
    for (int rt = 0; rt < 2; ++rt)
#pragma unroll
      for (int r = 0; r < 4; ++r) {
        int rl = rt * 16 + quad * 4 + r;
        sW[wv][rl] = i1[rt][r];
        if (b2[rt][r] - b1[rt][r] < MARGIN) {   // screen can't certify argmin
          int s = atomicAdd(&sFlagCnt, 1);      // LDS atomic: cheap
          sFlagRows[s] = rowbase + rl;
        }
      }
  }
  __syncthreads();
  // one global atomic per block (round-2's per-wave atomics serialized ~150us)
  if (tid == 0 && sFlagCnt > 0) sFlagBase = atomicAdd(cnt, sFlagCnt);
  __syncthreads();
  if (tid < sFlagCnt) list[sFlagBase + tid] = sFlagRows[tid];

  // tokens (as float; whole out buffer is fp32)
  if (lane < 32) tok[rowbase + lane] = (float)sW[wv][lane];

  // zq gather from fp32 codebook: 32 rows x 16 chunks of 16B, 8 per lane
#pragma unroll
  for (int i = 0; i < 8; ++i) {
    int cid = i * 64 + lane;
    int r32 = cid >> 4, seg = cid & 15;
    int widx = sW[wv][r32];
    float4 val = *(const float4*)(cb + (size_t)widx * D + seg * 4);
    *(float4*)(zq + (size_t)(rowbase + r32) * D + seg * 4) = val;
  }
}

// ---------------- exact fp32 fallback for flagged rows ----------------
// Same summation order as round-1's full-fp32 kernel (argmin matched np on all
// 65536 rows, absmax=0); float4 loads only change addressing, not fmaf order.
__global__ __launch_bounds__(256) void vq_fallback(
    const float* __restrict__ z, const float* __restrict__ cb,
    const int* __restrict__ cnt, const int* __restrict__ list,
    float* __restrict__ zq, float* __restrict__ tok) {
  __shared__ float sv[256];
  __shared__ int   si[256];
  const int t = threadIdx.x;
  const int n = cnt[0];
  for (int it = blockIdx.x; it < n; it += gridDim.x) {
    int row = __builtin_amdgcn_readfirstlane(list[it]);
    const float* zr = z + (size_t)row * D;
    float zreg[D];
#pragma unroll
    for (int i = 0; i < D / 4; ++i) {
      float4 q = ((const float4*)zr)[i];
      zreg[4 * i] = q.x; zreg[4 * i + 1] = q.y; zreg[4 * i + 2] = q.z; zreg[4 * i + 3] = q.w;
    }
    float d1 = 0.f;
#pragma unroll
    for (int i = 0; i < D; ++i) d1 = fmaf(zreg[i], zreg[i], d1);
    float best = FLT_MAX; int bidx = 0;
    for (int c = 0; c < 4; ++c) {
      int v = t + 256 * c;
      const float4* cp = (const float4*)(cb + (size_t)v * D);
      float acc = 0.f, cc = 0.f;
#pragma unroll
      for (int i = 0; i < D / 4; ++i) {
        float4 q = cp[i];
        acc = fmaf(zreg[4 * i], q.x, acc);     cc = fmaf(q.x, q.x, cc);
        acc = fmaf(zreg[4 * i + 1], q.y, acc); cc = fmaf(q.y, q.y, cc);
        acc = fmaf(zreg[4 * i + 2], q.z, acc); cc = fmaf(q.z, q.z, cc);
        acc = fmaf(zreg[4 * i + 3], q.w, acc); cc = fmaf(q.w, q.w, cc);
      }
      float dist = (d1 + cc) - 2.f * acc;
      if (dist < best) { best = dist; bidx = v; }
    }
    sv[t] = best; si[t] = bidx;
    __syncthreads();
    for (int s = 128; s > 0; s >>= 1) {
      if (t < s) {
        float v2 = sv[t + s]; int i2 = si[t + s];
        if (v2 < sv[t] || (v2 == sv[t] && i2 < si[t])) { sv[t] = v2; si[t] = i2; }
      }
      __syncthreads();
    }
    int win = si[0];
    if (t == 0) tok[row] = (float)win;
    if (t < 16) {
      float4 q = ((const float4*)(cb + (size_t)win * D))[t];
      ((float4*)(zq + (size_t)row * D))[t] = q;
    }
    __syncthreads();  // sv/si reused next iteration
  }
}

extern "C" void kernel_launch(void* const* d_in, const int* in_sizes, int n_in,
                              void* d_out, int out_size, void* d_ws, size_t ws_size,
                              hipStream_t stream) {
  const float* z  = (const float*)d_in[0];
  const float* cb = (const float*)d_in[1];

  float* out = (float*)d_out;
  float* zq  = out;                      // [NROWS*D]
  float* tok = out + (size_t)NROWS * D;  // [NROWS]
  float* cbo = tok + NROWS;              // [V*D]

  int* cnt  = (int*)d_ws;                // [1]
  int* list = (int*)d_ws + 64;           // [NROWS] worst-case flag list

  hipMemsetAsync(cnt, 0, sizeof(int), stream);
  vq_mfma<<<256, 512, 0, stream>>>(z, cb, zq, tok, cbo, cnt, list);
  vq_fallback<<<1024, 256, 0, stream>>>(z, cb, cnt, list, zq, tok);
}

// Round 4
// 141.476 us; speedup vs baseline: 4.5016x; 1.4730x over previous
//
#include <hip/hip_runtime.h>
#include <float.h>

// z: (64,32,32,64) fp32 -> N=65536 rows, D=64 ; codebook: (1024,64) fp32
// out concat fp32: zq [N*64] | tokens-as-float [N] | codebook [1024*64]
constexpr int D     = 64;
constexpr int V     = 1024;
constexpr int NROWS = 65536;
// Screen: split-f16 dot (zh*ch + zh*cl + zl*ch), |err| ~1e-5 vs exact;
// margin 0.01 certifies argmin with >=100x safety; ~0.5% rows fall back.
constexpr float MARGIN = 0.01f;

typedef _Float16 half8 __attribute__((ext_vector_type(8)));
typedef float    f32x4 __attribute__((ext_vector_type(4)));

// ---------------- main MFMA screen kernel ----------------
// 512 blocks x 256 threads (4 waves) -> 2 blocks/CU (LDS 66 KB; 132 KB/CU)
// so barrier drains of one block overlap compute of the other.
// Wave gw -> rows [gw*32, gw*32+32) as two 16-row MFMA tiles sharing B-frags.
// Codebook staged to LDS as f16 hi+lo in 4 phases of 256 codewords,
// chunk-major: sB*[k_octet][cw][8] so a B-frag (B[k=quad*8+j][n=lane&15])
// is one aligned ds_read_b128.
__global__ __launch_bounds__(256, 2) void vq_mfma(
    const float* __restrict__ z, const float* __restrict__ cb,
    float* __restrict__ zq, float* __restrict__ tok, float* __restrict__ cbout,
    int* __restrict__ cnt, int* __restrict__ list) {
  __shared__ __align__(16) _Float16 sBh[8][256][8];  // 32 KiB (hi)
  __shared__ __align__(16) _Float16 sBl[8][256][8];  // 32 KiB (lo)
  __shared__ float sC2[256];                         // |c|^2 per staged cw
  __shared__ int   sW[4][32];                        // winner idx per wave-row
  __shared__ int   sFlagRows[128];
  __shared__ int   sFlagCnt, sFlagBase;

  const int tid  = threadIdx.x;
  const int lane = tid & 63;
  const int wv   = tid >> 6;        // wave in block, 0..3
  const int l15  = lane & 15;
  const int quad = lane >> 4;       // 0..3
  const int gw   = blockIdx.x * 4 + wv;
  const int rowbase = gw * 32;

  if (tid == 0) sFlagCnt = 0;

  // codebook passthrough: 32 float4 per block x 512 blocks = 16384
  if (tid < 32)
    ((float4*)cbout)[blockIdx.x * 32 + tid] = ((const float4*)cb)[blockIdx.x * 32 + tid];

  // ---- A fragments hi/lo: rows rowbase + rt*16 + l15, k = quad*8 + j (+32*h) ----
  half8 afh[2][2], afl[2][2];
#pragma unroll
  for (int rt = 0; rt < 2; ++rt) {
    const float* zr = z + (size_t)(rowbase + rt * 16 + l15) * D;
#pragma unroll
    for (int h = 0; h < 2; ++h) {
      const float4* p = (const float4*)(zr + h * 32 + quad * 8);
      float4 q0 = p[0], q1 = p[1];
      float xs[8] = {q0.x, q0.y, q0.z, q0.w, q1.x, q1.y, q1.z, q1.w};
      half8 ah, al;
#pragma unroll
      for (int e = 0; e < 8; ++e) {
        _Float16 hi = (_Float16)xs[e];
        ah[e] = hi;
        al[e] = (_Float16)(xs[e] - (float)hi);
      }
      afh[rt][h] = ah; afl[rt][h] = al;
    }
  }

  // per-lane best / second-best screen value + best index, 4 C-regs x 2 row-tiles
  float b1[2][4], b2[2][4]; int i1[2][4];
#pragma unroll
  for (int rt = 0; rt < 2; ++rt)
#pragma unroll
    for (int r = 0; r < 4; ++r) { b1[rt][r] = FLT_MAX; b2[rt][r] = FLT_MAX; i1[rt][r] = 0; }

  for (int phase = 0; phase < 4; ++phase) {
    __syncthreads();  // previous compute done before LDS overwrite
    // ---- stage 256 codewords fp32 -> f16 hi+lo, plus |c|^2 ----
    // thread t stages codeword t of this phase (all 8 k-octets).
    {
      const float* src = cb + (size_t)(phase * 256 + tid) * D;
      float part = 0.f;
#pragma unroll
      for (int chunk = 0; chunk < 8; ++chunk) {
        float4 q0 = ((const float4*)(src + chunk * 8))[0];
        float4 q1 = ((const float4*)(src + chunk * 8))[1];
        float xs[8] = {q0.x, q0.y, q0.z, q0.w, q1.x, q1.y, q1.z, q1.w};
        half8 hh, hl;
#pragma unroll
        for (int e = 0; e < 8; ++e) {
          _Float16 hi = (_Float16)xs[e];
          hh[e] = hi;
          hl[e] = (_Float16)(xs[e] - (float)hi);
          part  = fmaf(xs[e], xs[e], part);
        }
        *(half8*)&sBh[chunk][tid][0] = hh;
        *(half8*)&sBl[chunk][tid][0] = hl;
      }
      sC2[tid] = part;
    }
    __syncthreads();
    // ---- 16 col-tiles of 16 codewords each ----
#pragma unroll 2
    for (int tl = 0; tl < 16; ++tl) {
      const int cwl  = tl * 16 + l15;
      const int vcol = phase * 256 + cwl;
      const float c2v = sC2[cwl];
      half8 bh0 = *(const half8*)&sBh[quad][cwl][0];      // k = quad*8+j
      half8 bh1 = *(const half8*)&sBh[4 + quad][cwl][0];  // k = 32+quad*8+j
      half8 bl0 = *(const half8*)&sBl[quad][cwl][0];
      half8 bl1 = *(const half8*)&sBl[4 + quad][cwl][0];
      f32x4 acc0 = {0.f, 0.f, 0.f, 0.f}, acc1 = {0.f, 0.f, 0.f, 0.f};
      acc0 = __builtin_amdgcn_mfma_f32_16x16x32_f16(afh[0][0], bh0, acc0, 0, 0, 0);
      acc0 = __builtin_amdgcn_mfma_f32_16x16x32_f16(afh[0][1], bh1, acc0, 0, 0, 0);
      acc0 = __builtin_amdgcn_mfma_f32_16x16x32_f16(afh[0][0], bl0, acc0, 0, 0, 0);
      acc0 = __builtin_amdgcn_mfma_f32_16x16x32_f16(afh[0][1], bl1, acc0, 0, 0, 0);
      acc0 = __builtin_amdgcn_mfma_f32_16x16x32_f16(afl[0][0], bh0, acc0, 0, 0, 0);
      acc0 = __builtin_amdgcn_mfma_f32_16x16x32_f16(afl[0][1], bh1, acc0, 0, 0, 0);

      acc1 = __builtin_amdgcn_mfma_f32_16x16x32_f16(afh[1][0], bh0, acc1, 0, 0, 0);
      acc1 = __builtin_amdgcn_mfma_f32_16x16x32_f16(afh[1][1], bh1, acc1, 0, 0, 0);
      acc1 = __builtin_amdgcn_mfma_f32_16x16x32_f16(afh[1][0], bl0, acc1, 0, 0, 0);
      acc1 = __builtin_amdgcn_mfma_f32_16x16x32_f16(afh[1][1], bl1, acc1, 0, 0, 0);
      acc1 = __builtin_amdgcn_mfma_f32_16x16x32_f16(afl[1][0], bh0, acc1, 0, 0, 0);
      acc1 = __builtin_amdgcn_mfma_f32_16x16x32_f16(afl[1][1], bh1, acc1, 0, 0, 0);
#pragma unroll
      for (int r = 0; r < 4; ++r) {
        float m0 = fmaf(-2.f, acc0[r], c2v);
        bool  c0 = m0 < b1[0][r];
        b2[0][r] = fminf(b2[0][r], fmaxf(m0, b1[0][r]));
        b1[0][r] = c0 ? m0 : b1[0][r];
        i1[0][r] = c0 ? vcol : i1[0][r];
        float m1 = fmaf(-2.f, acc1[r], c2v);
        bool  c1 = m1 < b1[1][r];
        b2[1][r] = fminf(b2[1][r], fmaxf(m1, b1[1][r]));
        b1[1][r] = c1 ? m1 : b1[1][r];
        i1[1][r] = c1 ? vcol : i1[1][r];
      }
    }
  }

  // ---- cross-lane reduce over the 16 col-lanes of each quad group ----
  // C layout: row = quad*4 + reg (within tile), col = l15. XOR 1/2/4/8 stays in-group.
#pragma unroll
  for (int rt = 0; rt < 2; ++rt)
#pragma unroll
    for (int r = 0; r < 4; ++r) {
      float v1 = b1[rt][r], v2 = b2[rt][r]; int ix = i1[rt][r];
#pragma unroll
      for (int s = 1; s < 16; s <<= 1) {
        float ov1 = __shfl_xor(v1, s);
        float ov2 = __shfl_xor(v2, s);
        int   oix = __shfl_xor(ix, s);
        bool take = (ov1 < v1) || (ov1 == v1 && oix < ix);  // np first-occurrence ties
        float worse = take ? v1 : ov1;
        v2 = fminf(fminf(v2, ov2), worse);
        v1 = take ? ov1 : v1;
        ix = take ? oix : ix;
      }
      b1[rt][r] = v1; b2[rt][r] = v2; i1[rt][r] = ix;
    }

  // writers: one lane per quad group publishes winners; flags queue in LDS
  if (l15 == 0) {
#pragma unroll
    for (int rt = 0; rt < 2; ++rt)
#pragma unroll
      for (int r = 0; r < 4; ++r) {
        int rl = rt * 16 + quad * 4 + r;
        sW[wv][rl] = i1[rt][r];
        if (b2[rt][r] - b1[rt][r] < MARGIN) {   // screen can't certify argmin
          int s = atomicAdd(&sFlagCnt, 1);      // LDS atomic: cheap
          sFlagRows[s] = rowbase + rl;
        }
      }
  }
  __syncthreads();
  // one global atomic per block
  if (tid == 0 && sFlagCnt > 0) sFlagBase = atomicAdd(cnt, sFlagCnt);
  __syncthreads();
  if (tid < sFlagCnt) list[sFlagBase + tid] = sFlagRows[tid];

  // tokens (as float; whole out buffer is fp32)
  if (lane < 32) tok[rowbase + lane] = (float)sW[wv][lane];

  // zq gather from fp32 codebook: 32 rows x 16 chunks of 16B, 8 per lane
#pragma unroll
  for (int i = 0; i < 8; ++i) {
    int cid = i * 64 + lane;
    int r32 = cid >> 4, seg = cid & 15;
    int widx = sW[wv][r32];
    float4 val = *(const float4*)(cb + (size_t)widx * D + seg * 4);
    *(float4*)(zq + (size_t)(rowbase + r32) * D + seg * 4) = val;
  }
}

// ---------------- exact fp32 fallback: one WAVE per flagged row ----------------
// Lane l scans codewords v = c*64 + l (16 each); byte-identical fmaf order to
// the round-1 full-fp32 kernel (argmin matched np exactly on all rows).
// No big per-thread arrays except the 64-float z row -> no scratch spill.
__global__ __launch_bounds__(256, 2) void vq_fallback(
    const float* __restrict__ z, const float* __restrict__ cb,
    const int* __restrict__ cnt, const int* __restrict__ list,
    float* __restrict__ zq, float* __restrict__ tok) {
  const int lane   = threadIdx.x & 63;
  const int waveId = blockIdx.x * 4 + (threadIdx.x >> 6);
  const int nWaves = gridDim.x * 4;
  const int n = cnt[0];

  for (int it = waveId; it < n; it += nWaves) {
    const int row = __builtin_amdgcn_readfirstlane(list[it]);
    const float* zr = z + (size_t)row * D;
    // z row (wave-uniform values) -> registers
    float zs[D];
#pragma unroll
    for (int i = 0; i < D / 4; ++i) {
      float4 q = ((const float4*)zr)[i];
      zs[4 * i] = q.x; zs[4 * i + 1] = q.y; zs[4 * i + 2] = q.z; zs[4 * i + 3] = q.w;
    }
    float d1 = 0.f;
#pragma unroll
    for (int i = 0; i < D; ++i) d1 = fmaf(zs[i], zs[i], d1);

    float best = FLT_MAX; int bidx = 0;
#pragma unroll 1
    for (int c = 0; c < 16; ++c) {
      const int v = c * 64 + lane;
      const float4* cp = (const float4*)(cb + (size_t)v * D);
      float acc = 0.f, cc = 0.f;
#pragma unroll
      for (int i = 0; i < D / 4; ++i) {
        float4 q = cp[i];
        acc = fmaf(zs[4 * i],     q.x, acc); cc = fmaf(q.x, q.x, cc);
        acc = fmaf(zs[4 * i + 1], q.y, acc); cc = fmaf(q.y, q.y, cc);
        acc = fmaf(zs[4 * i + 2], q.z, acc); cc = fmaf(q.z, q.z, cc);
        acc = fmaf(zs[4 * i + 3], q.w, acc); cc = fmaf(q.w, q.w, cc);
      }
      float dist = (d1 + cc) - 2.f * acc;
      if (dist < best || (dist == best && v < bidx)) { best = dist; bidx = v; }
    }
    // 64-lane argmin reduce, first-occurrence tie-break
#pragma unroll
    for (int s = 1; s < 64; s <<= 1) {
      float ov = __shfl_xor(best, s);
      int   oi = __shfl_xor(bidx, s);
      if (ov < best || (ov == best && oi < bidx)) { best = ov; bidx = oi; }
    }
    if (lane == 0) tok[row] = (float)bidx;
    if (lane < 16) {
      float4 q = ((const float4*)(cb + (size_t)bidx * D))[lane];
      ((float4*)(zq + (size_t)row * D))[lane] = q;
    }
  }
}

extern "C" void kernel_launch(void* const* d_in, const int* in_sizes, int n_in,
                              void* d_out, int out_size, void* d_ws, size_t ws_size,
                              hipStream_t stream) {
  const float* z  = (const float*)d_in[0];
  const float* cb = (const float*)d_in[1];

  float* out = (float*)d_out;
  float* zq  = out;                      // [NROWS*D]
  float* tok = out + (size_t)NROWS * D;  // [NROWS]
  float* cbo = tok + NROWS;              // [V*D]

  int* cnt  = (int*)d_ws;                // [1]
  int* list = (int*)d_ws + 64;           // [NROWS] worst-case flag list

  hipMemsetAsync(cnt, 0, sizeof(int), stream);
  vq_mfma<<<512, 256, 0, stream>>>(z, cb, zq, tok, cbo, cnt, list);
  vq_fallback<<<512, 256, 0, stream>>>(z, cb, cnt, list, zq, tok);
}